// Round 2
// baseline (4135.794 us; speedup 1.0000x reference)
//
#include <hip/hip_runtime.h>
#include <cstddef>

#define BATCH 32
#define TLEN  2048
#define HDIM  256
#define KDIM  512   // IX + IH
#define NDIM  1024  // 4 gates * H

// ---------------- pack weights: Wp[k][n], k in [0,512), n = gate*256 + j ----------------
__global__ void pack_w_kernel(const float* __restrict__ wix, const float* __restrict__ wih,
                              const float* __restrict__ wfx, const float* __restrict__ wfh,
                              const float* __restrict__ wcx, const float* __restrict__ wch,
                              const float* __restrict__ wox, const float* __restrict__ woh,
                              float* __restrict__ Wp) {
  int idx = blockIdx.x * blockDim.x + threadIdx.x;
  if (idx >= KDIM * NDIM) return;
  int n = idx & (NDIM - 1);
  int k = idx >> 10;
  int gate = n >> 8;
  int j = n & 255;
  const float* sx; const float* sh;
  if (gate == 0)      { sx = wix; sh = wih; }
  else if (gate == 1) { sx = wfx; sh = wfh; }
  else if (gate == 2) { sx = wcx; sh = wch; }
  else                { sx = wox; sh = woh; }
  Wp[idx] = (k < HDIM) ? sx[k * HDIM + j] : sh[(k - HDIM) * HDIM + j];
}

// ---------------- fused 4-gate pre-projection GEMM (fp32) ----------------
// C[m][n] = sum_k A[m][k] * Wp[k][n] + b_i[n&255]
// A[m][k] = x[m][k] (k<256) else h_prev[m][k-256];  m = b*T + t
#define BM 64
#define BN 64
#define BK 32

__global__ __launch_bounds__(256) void gemm_pre_kernel(
    const float* __restrict__ x, const float* __restrict__ hp,
    const float* __restrict__ Wp, const float* __restrict__ bi,
    float* __restrict__ pre) {
  __shared__ float As[BK][BM];   // transposed: As[k][m] -> b128 reads, 2-way conflict (free)
  __shared__ float Bs[BK][BN];
  const int tid = threadIdx.x;
  const int n0 = blockIdx.x * BN;   // ntile fast-varying: consecutive blocks share A m-tile in L2
  const int m0 = blockIdx.y * BM;
  const int tx = tid & 15;
  const int ty = tid >> 4;
  float acc[4][4] = {{0.f}};

  for (int k0 = 0; k0 < KDIM; k0 += BK) {
    // BK=32 tiles never straddle the x/h boundary (256 is a multiple of 32)
    const float* asrc = (k0 < HDIM) ? (x + k0) : (hp + (k0 - HDIM));
#pragma unroll
    for (int i = 0; i < 2; ++i) {
      const int f = tid + i * 256;          // 512 float4 loads for A, 512 for B
      const int row = f >> 3;               // A: 8 float4 per row of 64 rows
      const int c4 = (f & 7) * 4;
      const float4 a = *(const float4*)(asrc + (size_t)(m0 + row) * HDIM + c4);
      As[c4 + 0][row] = a.x;
      As[c4 + 1][row] = a.y;
      As[c4 + 2][row] = a.z;
      As[c4 + 3][row] = a.w;
      const int rB = f >> 4;                // B: 16 float4 per row of 32 rows
      const int cB = (f & 15) * 4;
      *(float4*)&Bs[rB][cB] = *(const float4*)(Wp + (size_t)(k0 + rB) * NDIM + n0 + cB);
    }
    __syncthreads();
#pragma unroll
    for (int kk = 0; kk < BK; ++kk) {
      const float4 av = *(const float4*)&As[kk][ty * 4];
      const float4 bv = *(const float4*)&Bs[kk][tx * 4];
      const float a[4] = {av.x, av.y, av.z, av.w};
      const float b[4] = {bv.x, bv.y, bv.z, bv.w};
#pragma unroll
      for (int r = 0; r < 4; ++r)
#pragma unroll
        for (int c = 0; c < 4; ++c)
          acc[r][c] = fmaf(a[r], b[c], acc[r][c]);
    }
    __syncthreads();
  }
  const int jb = (n0 & 255) + tx * 4;       // bias index, no wrap within float4 (n0 mult of 64)
  const float4 bias = *(const float4*)(bi + jb);
#pragma unroll
  for (int r = 0; r < 4; ++r) {
    const int m = m0 + ty * 4 + r;
    float4 v;
    v.x = acc[r][0] + bias.x;
    v.y = acc[r][1] + bias.y;
    v.z = acc[r][2] + bias.z;
    v.w = acc[r][3] + bias.w;
    *(float4*)(pre + (size_t)m * NDIM + n0 + tx * 4) = v;
  }
}

// ---------------- sequential scan: one workgroup per batch element ----------------
// Thread j owns output column j; u_i column j lives in 256 VGPRs (fully unrolled,
// static indices). h broadcast via LDS double buffer -> 1 barrier per step.
__global__ __launch_bounds__(256, 1) void scan_kernel(
    const float* __restrict__ pre, const float* __restrict__ ui,
    float* __restrict__ out) {
  const int b = blockIdx.x;
  const int j = threadIdx.x;
  __shared__ float hbuf[2][HDIM];

  float ucol[HDIM];
#pragma unroll
  for (int k = 0; k < HDIM; ++k) ucol[k] = ui[k * HDIM + j];  // coalesced across j

  hbuf[0][j] = 0.f;
  float c = 0.f;
  float h = 0.f;
  __syncthreads();

  const float* preb = pre + (size_t)b * TLEN * NDIM;
  float* hidden = out + 2 * BATCH * HDIM + (size_t)b * TLEN * HDIM;

  // prefetch t=0 pre-activations
  float pi = preb[j];
  float pf = preb[256 + j];
  float pg = preb[512 + j];
  float po = preb[768 + j];

  int p = 0;
  for (int t = 0; t < TLEN; ++t) {
    // prefetch next step's pre (hidden under this step's 256-FMA loop)
    const int tn = (t < TLEN - 1) ? t + 1 : t;
    const float* pn = preb + (size_t)tn * NDIM;
    const float npi = pn[j];
    const float npf = pn[256 + j];
    const float npg = pn[512 + j];
    const float npo = pn[768 + j];

    const float* hb = hbuf[p];
    float r0 = 0.f, r1 = 0.f, r2 = 0.f, r3 = 0.f;  // 4 chains break FMA latency
#pragma unroll
    for (int k4 = 0; k4 < HDIM / 4; ++k4) {
      const float4 h4 = *(const float4*)(hb + k4 * 4);  // uniform addr -> LDS broadcast
      r0 = fmaf(h4.x, ucol[k4 * 4 + 0], r0);
      r1 = fmaf(h4.y, ucol[k4 * 4 + 1], r1);
      r2 = fmaf(h4.z, ucol[k4 * 4 + 2], r2);
      r3 = fmaf(h4.w, ucol[k4 * 4 + 3], r3);
    }
    const float r = (r0 + r1) + (r2 + r3);

    const float gi = 1.f / (1.f + __expf(-(pi + r)));
    const float gf = 1.f / (1.f + __expf(-(pf + r)));
    const float gg = 1.f / (1.f + __expf(-(pg + r)));
    const float go = 1.f / (1.f + __expf(-(po + r)));
    c = gf + c + gi * gg;                                // reference quirk: f + c + i*g
    const float th = 1.f - 2.f / (__expf(2.f * c) + 1.f); // tanh, saturates safely (inf->1)
    h = go + th;                                          // reference quirk: o + tanh(c)

    hidden[(size_t)t * HDIM + j] = h;
    hbuf[p ^ 1][j] = h;
    __syncthreads();   // writes of hbuf[p^1] visible; all reads of hbuf[p] complete
    p ^= 1;
    pi = npi; pf = npf; pg = npg; po = npo;
  }
  out[b * HDIM + j] = h;                 // h_t  [B,H]
  out[BATCH * HDIM + b * HDIM + j] = c;  // c_t  [B,H]
}

extern "C" void kernel_launch(void* const* d_in, const int* in_sizes, int n_in,
                              void* d_out, int out_size, void* d_ws, size_t ws_size,
                              hipStream_t stream) {
  const float* x   = (const float*)d_in[0];
  const float* hp  = (const float*)d_in[1];
  const float* wix = (const float*)d_in[2];
  const float* wih = (const float*)d_in[3];
  const float* wfx = (const float*)d_in[4];
  const float* wfh = (const float*)d_in[5];
  const float* wcx = (const float*)d_in[6];
  const float* wch = (const float*)d_in[7];
  const float* wox = (const float*)d_in[8];
  const float* woh = (const float*)d_in[9];
  const float* ui  = (const float*)d_in[10];
  const float* bi  = (const float*)d_in[11];
  float* out = (float*)d_out;

  // ws layout: Wp [512*1024] f32 (2 MB) | pre [65536*1024] f32 (256 MB)
  float* Wp  = (float*)d_ws;
  float* pre = (float*)d_ws + (size_t)KDIM * NDIM;

  hipLaunchKernelGGL(pack_w_kernel, dim3((KDIM * NDIM) / 256), dim3(256), 0, stream,
                     wix, wih, wfx, wfh, wcx, wch, wox, woh, Wp);
  hipLaunchKernelGGL(gemm_pre_kernel, dim3(NDIM / BN, (BATCH * TLEN) / BM), dim3(256), 0, stream,
                     x, hp, Wp, bi, pre);
  hipLaunchKernelGGL(scan_kernel, dim3(BATCH), dim3(256), 0, stream, pre, ui, out);
}

// Round 4
// 3883.392 us; speedup vs baseline: 1.0650x; 1.0650x over previous
//
#include <hip/hip_runtime.h>
#include <cstddef>

#define BATCH 32
#define TLEN  2048
#define HDIM  256
#define KDIM  512   // IX + IH
#define NDIM  1024  // 4 gates * H
#define SPLIT 2     // k-split of the recurrent matvec

// ---------------- pack weights: Wp[k][n], k in [0,512), n = gate*256 + j ----------------
__global__ void pack_w_kernel(const float* __restrict__ wix, const float* __restrict__ wih,
                              const float* __restrict__ wfx, const float* __restrict__ wfh,
                              const float* __restrict__ wcx, const float* __restrict__ wch,
                              const float* __restrict__ wox, const float* __restrict__ woh,
                              float* __restrict__ Wp) {
  int idx = blockIdx.x * blockDim.x + threadIdx.x;
  if (idx >= KDIM * NDIM) return;
  int n = idx & (NDIM - 1);
  int k = idx >> 10;
  int gate = n >> 8;
  int j = n & 255;
  const float* sx; const float* sh;
  if (gate == 0)      { sx = wix; sh = wih; }
  else if (gate == 1) { sx = wfx; sh = wfh; }
  else if (gate == 2) { sx = wcx; sh = wch; }
  else                { sx = wox; sh = woh; }
  Wp[idx] = (k < HDIM) ? sx[k * HDIM + j] : sh[(k - HDIM) * HDIM + j];
}

// ---------------- fused 4-gate pre-projection GEMM (fp32) ---------------- (unchanged)
#define BM 64
#define BN 64
#define BK 32

__global__ __launch_bounds__(256) void gemm_pre_kernel(
    const float* __restrict__ x, const float* __restrict__ hp,
    const float* __restrict__ Wp, const float* __restrict__ bi,
    float* __restrict__ pre) {
  __shared__ float As[BK][BM];
  __shared__ float Bs[BK][BN];
  const int tid = threadIdx.x;
  const int n0 = blockIdx.x * BN;
  const int m0 = blockIdx.y * BM;
  const int tx = tid & 15;
  const int ty = tid >> 4;
  float acc[4][4] = {{0.f}};

  for (int k0 = 0; k0 < KDIM; k0 += BK) {
    const float* asrc = (k0 < HDIM) ? (x + k0) : (hp + (k0 - HDIM));
#pragma unroll
    for (int i = 0; i < 2; ++i) {
      const int f = tid + i * 256;
      const int row = f >> 3;
      const int c4 = (f & 7) * 4;
      const float4 a = *(const float4*)(asrc + (size_t)(m0 + row) * HDIM + c4);
      As[c4 + 0][row] = a.x;
      As[c4 + 1][row] = a.y;
      As[c4 + 2][row] = a.z;
      As[c4 + 3][row] = a.w;
      const int rB = f >> 4;
      const int cB = (f & 15) * 4;
      *(float4*)&Bs[rB][cB] = *(const float4*)(Wp + (size_t)(k0 + rB) * NDIM + n0 + cB);
    }
    __syncthreads();
#pragma unroll
    for (int kk = 0; kk < BK; ++kk) {
      const float4 av = *(const float4*)&As[kk][ty * 4];
      const float4 bv = *(const float4*)&Bs[kk][tx * 4];
      const float a[4] = {av.x, av.y, av.z, av.w};
      const float b[4] = {bv.x, bv.y, bv.z, bv.w};
#pragma unroll
      for (int r = 0; r < 4; ++r)
#pragma unroll
        for (int c = 0; c < 4; ++c)
          acc[r][c] = fmaf(a[r], b[c], acc[r][c]);
    }
    __syncthreads();
  }
  const int jb = (n0 & 255) + tx * 4;
  const float4 bias = *(const float4*)(bi + jb);
#pragma unroll
  for (int r = 0; r < 4; ++r) {
    const int m = m0 + ty * 4 + r;
    float4 v;
    v.x = acc[r][0] + bias.x;
    v.y = acc[r][1] + bias.y;
    v.z = acc[r][2] + bias.z;
    v.w = acc[r][3] + bias.w;
    *(float4*)(pre + (size_t)m * NDIM + n0 + tx * 4) = v;
  }
}

// ---------------- sequential scan v2: 512 threads, 2-way k-split ----------------
// Thread (ks, j): ks = tid>>8 owns k-range [ks*128, ks*128+128) of u_i column j.
// ucol[128] stays in VGPRs (170 total < 256 cap from launch_bounds(512,2) -> no spill,
// the round-2 failure mode at 256/thread with VGPR_Count=160).
// Phase A (all 8 waves): partial dot, reduce via rbuf. Phase B (waves 0-3, one per
// SIMD): gates + state update. Barriers outside divergent regions.
__global__ __launch_bounds__(512, 2) void scan_kernel(
    const float* __restrict__ pre, const float* __restrict__ ui,
    float* __restrict__ out) {
  const int b = blockIdx.x;
  const int tid = threadIdx.x;
  const int j = tid & (HDIM - 1);
  const int ks = tid >> 8;                 // 0..SPLIT-1
  __shared__ float hbuf[2][HDIM];
  __shared__ float rbuf[SPLIT][HDIM];

  float ucol[HDIM / SPLIT];                // 128 VGPRs, static indices after unroll
#pragma unroll
  for (int k = 0; k < HDIM / SPLIT; ++k)
    ucol[k] = ui[(size_t)(ks * (HDIM / SPLIT) + k) * HDIM + j];  // coalesced across j

  if (tid < HDIM) hbuf[0][tid] = 0.f;
  float c = 0.f, h = 0.f;

  const float* preb = pre + (size_t)b * TLEN * NDIM;
  float* hidden = out + 2 * BATCH * HDIM + (size_t)b * TLEN * HDIM;

  float pi = 0.f, pf = 0.f, pg = 0.f, po = 0.f;
  if (ks == 0) {
    pi = preb[j]; pf = preb[256 + j]; pg = preb[512 + j]; po = preb[768 + j];
  }
  __syncthreads();

  int p = 0;
  for (int t = 0; t < TLEN; ++t) {
    // prefetch t+1 pre-activations (ks==0 only); latency hides under phase A
    float npi = 0.f, npf = 0.f, npg = 0.f, npo = 0.f;
    if (ks == 0) {
      const int tn = (t < TLEN - 1) ? t + 1 : t;
      const float* pn = preb + (size_t)tn * NDIM;
      npi = pn[j]; npf = pn[256 + j]; npg = pn[512 + j]; npo = pn[768 + j];
    }

    // ---- phase A: partial recurrent dot (all waves) ----
    const float* hb = hbuf[p] + ks * (HDIM / SPLIT);
    float r0 = 0.f, r1 = 0.f, r2 = 0.f, r3 = 0.f;
#pragma unroll
    for (int k4 = 0; k4 < HDIM / SPLIT / 4; ++k4) {
      const float4 h4 = *(const float4*)(hb + k4 * 4);  // wave-uniform addr -> broadcast
      r0 = fmaf(h4.x, ucol[k4 * 4 + 0], r0);
      r1 = fmaf(h4.y, ucol[k4 * 4 + 1], r1);
      r2 = fmaf(h4.z, ucol[k4 * 4 + 2], r2);
      r3 = fmaf(h4.w, ucol[k4 * 4 + 3], r3);
    }
    rbuf[ks][j] = (r0 + r1) + (r2 + r3);
    __syncthreads();

    // ---- phase B: gates + state update (waves 0-3, one per SIMD) ----
    if (ks == 0) {
      const float r = rbuf[0][j] + rbuf[1][j];
      const float gi = 1.f / (1.f + __expf(-(pi + r)));
      const float gf = 1.f / (1.f + __expf(-(pf + r)));
      const float gg = 1.f / (1.f + __expf(-(pg + r)));
      const float go = 1.f / (1.f + __expf(-(po + r)));
      c = gf + c + gi * gg;                                 // reference quirk: f + c + i*g
      const float th = 1.f - 2.f / (__expf(2.f * c) + 1.f); // tanh, inf-safe
      h = go + th;                                          // reference quirk: o + tanh(c)
      hidden[(size_t)t * HDIM + j] = h;
      hbuf[p ^ 1][j] = h;
      pi = npi; pf = npf; pg = npg; po = npo;
    }
    __syncthreads();  // hbuf[p^1] visible to all; rbuf reads done before next overwrite
    p ^= 1;
  }
  if (ks == 0) {
    out[b * HDIM + j] = h;                 // h_t  [B,H]
    out[BATCH * HDIM + b * HDIM + j] = c;  // c_t  [B,H]
  }
}

extern "C" void kernel_launch(void* const* d_in, const int* in_sizes, int n_in,
                              void* d_out, int out_size, void* d_ws, size_t ws_size,
                              hipStream_t stream) {
  const float* x   = (const float*)d_in[0];
  const float* hp  = (const float*)d_in[1];
  const float* wix = (const float*)d_in[2];
  const float* wih = (const float*)d_in[3];
  const float* wfx = (const float*)d_in[4];
  const float* wfh = (const float*)d_in[5];
  const float* wcx = (const float*)d_in[6];
  const float* wch = (const float*)d_in[7];
  const float* wox = (const float*)d_in[8];
  const float* woh = (const float*)d_in[9];
  const float* ui  = (const float*)d_in[10];
  const float* bi  = (const float*)d_in[11];
  float* out = (float*)d_out;

  // ws layout: Wp [512*1024] f32 (2 MB) | pre [65536*1024] f32 (256 MB)
  float* Wp  = (float*)d_ws;
  float* pre = (float*)d_ws + (size_t)KDIM * NDIM;

  hipLaunchKernelGGL(pack_w_kernel, dim3((KDIM * NDIM) / 256), dim3(256), 0, stream,
                     wix, wih, wfx, wfh, wcx, wch, wox, woh, Wp);
  hipLaunchKernelGGL(gemm_pre_kernel, dim3(NDIM / BN, (BATCH * TLEN) / BM), dim3(256), 0, stream,
                     x, hp, Wp, bi, pre);
  hipLaunchKernelGGL(scan_kernel, dim3(BATCH), dim3(512), 0, stream, pre, ui, out);
}

// Round 5
// 2878.760 us; speedup vs baseline: 1.4367x; 1.3490x over previous
//
#include <hip/hip_runtime.h>
#include <cstddef>

#define BATCH 32
#define TLEN  2048
#define HDIM  256
#define KDIM  512   // IX + IH
#define NDIM  1024  // 4 gates * H

// ---------------- pack weights: Wp[k][n], k in [0,512), n = gate*256 + j ----------------
__global__ void pack_w_kernel(const float* __restrict__ wix, const float* __restrict__ wih,
                              const float* __restrict__ wfx, const float* __restrict__ wfh,
                              const float* __restrict__ wcx, const float* __restrict__ wch,
                              const float* __restrict__ wox, const float* __restrict__ woh,
                              float* __restrict__ Wp) {
  int idx = blockIdx.x * blockDim.x + threadIdx.x;
  if (idx >= KDIM * NDIM) return;
  int n = idx & (NDIM - 1);
  int k = idx >> 10;
  int gate = n >> 8;
  int j = n & 255;
  const float* sx; const float* sh;
  if (gate == 0)      { sx = wix; sh = wih; }
  else if (gate == 1) { sx = wfx; sh = wfh; }
  else if (gate == 2) { sx = wcx; sh = wch; }
  else                { sx = wox; sh = woh; }
  Wp[idx] = (k < HDIM) ? sx[k * HDIM + j] : sh[(k - HDIM) * HDIM + j];
}

// ---------------- fused 4-gate pre-projection GEMM (fp32) ---------------- (unchanged)
#define BM 64
#define BN 64
#define BK 32

__global__ __launch_bounds__(256) void gemm_pre_kernel(
    const float* __restrict__ x, const float* __restrict__ hp,
    const float* __restrict__ Wp, const float* __restrict__ bi,
    float* __restrict__ pre) {
  __shared__ float As[BK][BM];
  __shared__ float Bs[BK][BN];
  const int tid = threadIdx.x;
  const int n0 = blockIdx.x * BN;
  const int m0 = blockIdx.y * BM;
  const int tx = tid & 15;
  const int ty = tid >> 4;
  float acc[4][4] = {{0.f}};

  for (int k0 = 0; k0 < KDIM; k0 += BK) {
    const float* asrc = (k0 < HDIM) ? (x + k0) : (hp + (k0 - HDIM));
#pragma unroll
    for (int i = 0; i < 2; ++i) {
      const int f = tid + i * 256;
      const int row = f >> 3;
      const int c4 = (f & 7) * 4;
      const float4 a = *(const float4*)(asrc + (size_t)(m0 + row) * HDIM + c4);
      As[c4 + 0][row] = a.x;
      As[c4 + 1][row] = a.y;
      As[c4 + 2][row] = a.z;
      As[c4 + 3][row] = a.w;
      const int rB = f >> 4;
      const int cB = (f & 15) * 4;
      *(float4*)&Bs[rB][cB] = *(const float4*)(Wp + (size_t)(k0 + rB) * NDIM + n0 + cB);
    }
    __syncthreads();
#pragma unroll
    for (int kk = 0; kk < BK; ++kk) {
      const float4 av = *(const float4*)&As[kk][ty * 4];
      const float4 bv = *(const float4*)&Bs[kk][tx * 4];
      const float a[4] = {av.x, av.y, av.z, av.w};
      const float b[4] = {bv.x, bv.y, bv.z, bv.w};
#pragma unroll
      for (int r = 0; r < 4; ++r)
#pragma unroll
        for (int c = 0; c < 4; ++c)
          acc[r][c] = fmaf(a[r], b[c], acc[r][c]);
    }
    __syncthreads();
  }
  const int jb = (n0 & 255) + tx * 4;
  const float4 bias = *(const float4*)(bi + jb);
#pragma unroll
  for (int r = 0; r < 4; ++r) {
    const int m = m0 + ty * 4 + r;
    float4 v;
    v.x = acc[r][0] + bias.x;
    v.y = acc[r][1] + bias.y;
    v.z = acc[r][2] + bias.z;
    v.w = acc[r][3] + bias.w;
    *(float4*)(pre + (size_t)m * NDIM + n0 + tx * 4) = v;
  }
}

// ---------------- sequential scan v3: 8 waves, K=32 per wave, J=4 per thread ----------------
// Wave w owns k-range [32w, 32w+32) -> h-reads are wave-uniform (pure LDS broadcast),
// only 8 ds_read_b128 per wave per step (vs 32 in v2: LDS pipe was the bottleneck,
// 256 bcast instrs ~= 3072 cy/step matched observed 3340).
// Thread (w, cg) computes partials for columns {cg, cg+64, cg+128, cg+192}.
// u-slice = 32 named const float4 (forces VGPR residency; v1/v2 arrays got demoted,
// VGPR_Count=160/104 proved it). 8-way reduction via rbuf, conflict-free both sides.
__global__ __launch_bounds__(512, 2) void scan_kernel(
    const float* __restrict__ pre, const float* __restrict__ ui,
    float* __restrict__ out) {
  const int b   = blockIdx.x;
  const int tid = threadIdx.x;
  const int w   = tid >> 6;   // wave id = k-split slot
  const int cg  = tid & 63;   // column group
  __shared__ float hbuf[HDIM];
  __shared__ float rbuf[8][4][64];

  // ---- load u-slice into 32 named float4 registers ----
  const float* ub = ui + (32 * w) * HDIM + cg;   // row 32w, col cg
#define ULOAD(K) const float4 u##K = make_float4( \
    ub[(K) * HDIM], ub[(K) * HDIM + 64], ub[(K) * HDIM + 128], ub[(K) * HDIM + 192]);
  ULOAD(0)  ULOAD(1)  ULOAD(2)  ULOAD(3)  ULOAD(4)  ULOAD(5)  ULOAD(6)  ULOAD(7)
  ULOAD(8)  ULOAD(9)  ULOAD(10) ULOAD(11) ULOAD(12) ULOAD(13) ULOAD(14) ULOAD(15)
  ULOAD(16) ULOAD(17) ULOAD(18) ULOAD(19) ULOAD(20) ULOAD(21) ULOAD(22) ULOAD(23)
  ULOAD(24) ULOAD(25) ULOAD(26) ULOAD(27) ULOAD(28) ULOAD(29) ULOAD(30) ULOAD(31)
#undef ULOAD

  const float* preb = pre + (size_t)b * TLEN * NDIM;
  float* hidden = out + 2 * BATCH * HDIM + (size_t)b * TLEN * HDIM;

  float pi = 0.f, pf = 0.f, pg = 0.f, po = 0.f;
  float c = 0.f, h = 0.f;
  if (tid < HDIM) {
    hbuf[tid] = 0.f;
    pi = preb[tid]; pf = preb[256 + tid]; pg = preb[512 + tid]; po = preb[768 + tid];
  }
  __syncthreads();

  const float* hb = &hbuf[w * 32];

  for (int t = 0; t < TLEN; ++t) {
    // prefetch t+1 pre (one full step of latency hiding)
    float npi = 0.f, npf = 0.f, npg = 0.f, npo = 0.f;
    if (tid < HDIM) {
      const int tn = (t < TLEN - 1) ? t + 1 : t;
      const float* pn = preb + (size_t)tn * NDIM;
      npi = pn[tid]; npf = pn[256 + tid]; npg = pn[512 + tid]; npo = pn[768 + tid];
    }

    // ---- phase A: 32 k-steps, 4 columns each; h via wave-uniform b128 broadcast ----
    float4 acc = make_float4(0.f, 0.f, 0.f, 0.f);
#define KQ(K4, UA, UB, UC, UD) { \
    const float4 hv = *(const float4*)(hb + 4 * (K4)); \
    acc.x = fmaf(hv.x, UA.x, acc.x); acc.y = fmaf(hv.x, UA.y, acc.y); \
    acc.z = fmaf(hv.x, UA.z, acc.z); acc.w = fmaf(hv.x, UA.w, acc.w); \
    acc.x = fmaf(hv.y, UB.x, acc.x); acc.y = fmaf(hv.y, UB.y, acc.y); \
    acc.z = fmaf(hv.y, UB.z, acc.z); acc.w = fmaf(hv.y, UB.w, acc.w); \
    acc.x = fmaf(hv.z, UC.x, acc.x); acc.y = fmaf(hv.z, UC.y, acc.y); \
    acc.z = fmaf(hv.z, UC.z, acc.z); acc.w = fmaf(hv.z, UC.w, acc.w); \
    acc.x = fmaf(hv.w, UD.x, acc.x); acc.y = fmaf(hv.w, UD.y, acc.y); \
    acc.z = fmaf(hv.w, UD.z, acc.z); acc.w = fmaf(hv.w, UD.w, acc.w); }
    KQ(0, u0,  u1,  u2,  u3)
    KQ(1, u4,  u5,  u6,  u7)
    KQ(2, u8,  u9,  u10, u11)
    KQ(3, u12, u13, u14, u15)
    KQ(4, u16, u17, u18, u19)
    KQ(5, u20, u21, u22, u23)
    KQ(6, u24, u25, u26, u27)
    KQ(7, u28, u29, u30, u31)
#undef KQ

    // partial write: [w][jj][cg] -> lanes stride-1 in cg, conflict-free
    rbuf[w][0][cg] = acc.x;
    rbuf[w][1][cg] = acc.y;
    rbuf[w][2][cg] = acc.z;
    rbuf[w][3][cg] = acc.w;
    __syncthreads();

    // ---- phase B: waves 0-3 (thread j = tid < 256): reduce + gates + state ----
    if (tid < HDIM) {
      const int jjf = tid >> 6;   // wave-uniform -> conflict-free stride-1 reads
      const int cgf = tid & 63;
      float r = 0.f;
#pragma unroll
      for (int w2 = 0; w2 < 8; ++w2) r += rbuf[w2][jjf][cgf];

      const float gi = 1.f / (1.f + __expf(-(pi + r)));
      const float gf = 1.f / (1.f + __expf(-(pf + r)));
      const float gg = 1.f / (1.f + __expf(-(pg + r)));
      const float go = 1.f / (1.f + __expf(-(po + r)));
      c = gf + c + gi * gg;                                 // reference quirk: f + c + i*g
      const float th = 1.f - 2.f / (__expf(2.f * c) + 1.f); // tanh, inf-safe
      h = go + th;                                          // reference quirk: o + tanh(c)

      hidden[(size_t)t * HDIM + tid] = h;
      hbuf[tid] = h;                 // safe: all phase-A reads done at barrier above
      pi = npi; pf = npf; pg = npg; po = npo;
    }
    __syncthreads();                 // new h visible before next phase A
  }
  if (tid < HDIM) {
    out[b * HDIM + tid] = h;                 // h_t  [B,H]
    out[BATCH * HDIM + b * HDIM + tid] = c;  // c_t  [B,H]
  }
}

extern "C" void kernel_launch(void* const* d_in, const int* in_sizes, int n_in,
                              void* d_out, int out_size, void* d_ws, size_t ws_size,
                              hipStream_t stream) {
  const float* x   = (const float*)d_in[0];
  const float* hp  = (const float*)d_in[1];
  const float* wix = (const float*)d_in[2];
  const float* wih = (const float*)d_in[3];
  const float* wfx = (const float*)d_in[4];
  const float* wfh = (const float*)d_in[5];
  const float* wcx = (const float*)d_in[6];
  const float* wch = (const float*)d_in[7];
  const float* wox = (const float*)d_in[8];
  const float* woh = (const float*)d_in[9];
  const float* ui  = (const float*)d_in[10];
  const float* bi  = (const float*)d_in[11];
  float* out = (float*)d_out;

  // ws layout: Wp [512*1024] f32 (2 MB) | pre [65536*1024] f32 (256 MB)
  float* Wp  = (float*)d_ws;
  float* pre = (float*)d_ws + (size_t)KDIM * NDIM;

  hipLaunchKernelGGL(pack_w_kernel, dim3((KDIM * NDIM) / 256), dim3(256), 0, stream,
                     wix, wih, wfx, wfh, wcx, wch, wox, woh, Wp);
  hipLaunchKernelGGL(gemm_pre_kernel, dim3(NDIM / BN, (BATCH * TLEN) / BM), dim3(256), 0, stream,
                     x, hp, Wp, bi, pre);
  hipLaunchKernelGGL(scan_kernel, dim3(BATCH), dim3(512), 0, stream, pre, ui, out);
}

// Round 6
// 2663.592 us; speedup vs baseline: 1.5527x; 1.0808x over previous
//
#include <hip/hip_runtime.h>
#include <cstddef>

#define BATCH 32
#define TLEN  2048
#define HDIM  256
#define KDIM  512   // IX + IH
#define NDIM  1024  // 4 gates * H

typedef float f32x4 __attribute__((ext_vector_type(4)));

// ---------------- pack weights: Wp[k][n], k in [0,512), n = gate*256 + j ----------------
__global__ void pack_w_kernel(const float* __restrict__ wix, const float* __restrict__ wih,
                              const float* __restrict__ wfx, const float* __restrict__ wfh,
                              const float* __restrict__ wcx, const float* __restrict__ wch,
                              const float* __restrict__ wox, const float* __restrict__ woh,
                              float* __restrict__ Wp) {
  int idx = blockIdx.x * blockDim.x + threadIdx.x;
  if (idx >= KDIM * NDIM) return;
  int n = idx & (NDIM - 1);
  int k = idx >> 10;
  int gate = n >> 8;
  int j = n & 255;
  const float* sx; const float* sh;
  if (gate == 0)      { sx = wix; sh = wih; }
  else if (gate == 1) { sx = wfx; sh = wfh; }
  else if (gate == 2) { sx = wcx; sh = wch; }
  else                { sx = wox; sh = woh; }
  Wp[idx] = (k < HDIM) ? sx[k * HDIM + j] : sh[(k - HDIM) * HDIM + j];
}

// ---------------- fused 4-gate pre-projection GEMM (fp32) ---------------- (unchanged)
#define BM 64
#define BN 64
#define BK 32

__global__ __launch_bounds__(256) void gemm_pre_kernel(
    const float* __restrict__ x, const float* __restrict__ hp,
    const float* __restrict__ Wp, const float* __restrict__ bi,
    float* __restrict__ pre) {
  __shared__ float As[BK][BM];
  __shared__ float Bs[BK][BN];
  const int tid = threadIdx.x;
  const int n0 = blockIdx.x * BN;
  const int m0 = blockIdx.y * BM;
  const int tx = tid & 15;
  const int ty = tid >> 4;
  float acc[4][4] = {{0.f}};

  for (int k0 = 0; k0 < KDIM; k0 += BK) {
    const float* asrc = (k0 < HDIM) ? (x + k0) : (hp + (k0 - HDIM));
#pragma unroll
    for (int i = 0; i < 2; ++i) {
      const int f = tid + i * 256;
      const int row = f >> 3;
      const int c4 = (f & 7) * 4;
      const float4 a = *(const float4*)(asrc + (size_t)(m0 + row) * HDIM + c4);
      As[c4 + 0][row] = a.x;
      As[c4 + 1][row] = a.y;
      As[c4 + 2][row] = a.z;
      As[c4 + 3][row] = a.w;
      const int rB = f >> 4;
      const int cB = (f & 15) * 4;
      *(float4*)&Bs[rB][cB] = *(const float4*)(Wp + (size_t)(k0 + rB) * NDIM + n0 + cB);
    }
    __syncthreads();
#pragma unroll
    for (int kk = 0; kk < BK; ++kk) {
      const float4 av = *(const float4*)&As[kk][ty * 4];
      const float4 bv = *(const float4*)&Bs[kk][tx * 4];
      const float a[4] = {av.x, av.y, av.z, av.w};
      const float b[4] = {bv.x, bv.y, bv.z, bv.w};
#pragma unroll
      for (int r = 0; r < 4; ++r)
#pragma unroll
        for (int c = 0; c < 4; ++c)
          acc[r][c] = fmaf(a[r], b[c], acc[r][c]);
    }
    __syncthreads();
  }
  const int jb = (n0 & 255) + tx * 4;
  const float4 bias = *(const float4*)(bi + jb);
#pragma unroll
  for (int r = 0; r < 4; ++r) {
    const int m = m0 + ty * 4 + r;
    float4 v;
    v.x = acc[r][0] + bias.x;
    v.y = acc[r][1] + bias.y;
    v.z = acc[r][2] + bias.z;
    v.w = acc[r][3] + bias.w;
    *(float4*)(pre + (size_t)m * NDIM + n0 + tx * 4) = v;
  }
}

// ---------------- sequential scan v4: v3 + asm-pinned u registers ----------------
// v3 result: VGPR_Count=84 -> compiler re-loaded the 128-float u-slice from L1/L2
// every step (~1100 extra cy/step). Fix: "+v" empty-asm pin INSIDE the loop makes
// the values asm-opaque (cannot be rematerialized from memory) -> true VGPR
// residency. 128 u + ~40 working < 256 cap from launch_bounds(512,2).
__global__ __launch_bounds__(512, 2) void scan_kernel(
    const float* __restrict__ pre, const float* __restrict__ ui,
    float* __restrict__ out) {
  const int b   = blockIdx.x;
  const int tid = threadIdx.x;
  const int w   = tid >> 6;   // wave id = k-split slot
  const int cg  = tid & 63;   // column group
  __shared__ float hbuf[HDIM];
  __shared__ float rbuf[8][4][64];

  // ---- load u-slice into 32 f32x4 registers (once) ----
  const float* ub = ui + (32 * w) * HDIM + cg;   // row 32w, col cg
#define ULOAD(K) f32x4 u##K = { \
    ub[(K) * HDIM], ub[(K) * HDIM + 64], ub[(K) * HDIM + 128], ub[(K) * HDIM + 192]};
  ULOAD(0)  ULOAD(1)  ULOAD(2)  ULOAD(3)  ULOAD(4)  ULOAD(5)  ULOAD(6)  ULOAD(7)
  ULOAD(8)  ULOAD(9)  ULOAD(10) ULOAD(11) ULOAD(12) ULOAD(13) ULOAD(14) ULOAD(15)
  ULOAD(16) ULOAD(17) ULOAD(18) ULOAD(19) ULOAD(20) ULOAD(21) ULOAD(22) ULOAD(23)
  ULOAD(24) ULOAD(25) ULOAD(26) ULOAD(27) ULOAD(28) ULOAD(29) ULOAD(30) ULOAD(31)
#undef ULOAD

  const float* preb = pre + (size_t)b * TLEN * NDIM;
  float* hidden = out + 2 * BATCH * HDIM + (size_t)b * TLEN * HDIM;

  float pi = 0.f, pf = 0.f, pg = 0.f, po = 0.f;
  float c = 0.f, h = 0.f;
  if (tid < HDIM) {
    hbuf[tid] = 0.f;
    pi = preb[tid]; pf = preb[256 + tid]; pg = preb[512 + tid]; po = preb[768 + tid];
  }
  __syncthreads();

  const float* hb = &hbuf[w * 32];

  for (int t = 0; t < TLEN; ++t) {
    // pin u in VGPRs: asm-opaque read-write use defeats remat-by-reload (round-5
    // failure mode: VGPR_Count=84, u re-fetched from cache every step)
    asm volatile("" : "+v"(u0),  "+v"(u1),  "+v"(u2),  "+v"(u3));
    asm volatile("" : "+v"(u4),  "+v"(u5),  "+v"(u6),  "+v"(u7));
    asm volatile("" : "+v"(u8),  "+v"(u9),  "+v"(u10), "+v"(u11));
    asm volatile("" : "+v"(u12), "+v"(u13), "+v"(u14), "+v"(u15));
    asm volatile("" : "+v"(u16), "+v"(u17), "+v"(u18), "+v"(u19));
    asm volatile("" : "+v"(u20), "+v"(u21), "+v"(u22), "+v"(u23));
    asm volatile("" : "+v"(u24), "+v"(u25), "+v"(u26), "+v"(u27));
    asm volatile("" : "+v"(u28), "+v"(u29), "+v"(u30), "+v"(u31));

    // prefetch t+1 pre (one full step of latency hiding)
    float npi = 0.f, npf = 0.f, npg = 0.f, npo = 0.f;
    if (tid < HDIM) {
      const int tn = (t < TLEN - 1) ? t + 1 : t;
      const float* pn = preb + (size_t)tn * NDIM;
      npi = pn[tid]; npf = pn[256 + tid]; npg = pn[512 + tid]; npo = pn[768 + tid];
    }

    // ---- phase A: 32 k-steps, 4 columns each; h via wave-uniform b128 broadcast ----
    f32x4 acc = {0.f, 0.f, 0.f, 0.f};
#define KQ(K4, UA, UB, UC, UD) { \
    const f32x4 hv = *(const f32x4*)(hb + 4 * (K4)); \
    acc.x = fmaf(hv.x, UA.x, acc.x); acc.y = fmaf(hv.x, UA.y, acc.y); \
    acc.z = fmaf(hv.x, UA.z, acc.z); acc.w = fmaf(hv.x, UA.w, acc.w); \
    acc.x = fmaf(hv.y, UB.x, acc.x); acc.y = fmaf(hv.y, UB.y, acc.y); \
    acc.z = fmaf(hv.y, UB.z, acc.z); acc.w = fmaf(hv.y, UB.w, acc.w); \
    acc.x = fmaf(hv.z, UC.x, acc.x); acc.y = fmaf(hv.z, UC.y, acc.y); \
    acc.z = fmaf(hv.z, UC.z, acc.z); acc.w = fmaf(hv.z, UC.w, acc.w); \
    acc.x = fmaf(hv.w, UD.x, acc.x); acc.y = fmaf(hv.w, UD.y, acc.y); \
    acc.z = fmaf(hv.w, UD.z, acc.z); acc.w = fmaf(hv.w, UD.w, acc.w); }
    KQ(0, u0,  u1,  u2,  u3)
    KQ(1, u4,  u5,  u6,  u7)
    KQ(2, u8,  u9,  u10, u11)
    KQ(3, u12, u13, u14, u15)
    KQ(4, u16, u17, u18, u19)
    KQ(5, u20, u21, u22, u23)
    KQ(6, u24, u25, u26, u27)
    KQ(7, u28, u29, u30, u31)
#undef KQ

    // partial write: [w][jj][cg] -> lanes stride-1 in cg, conflict-free
    rbuf[w][0][cg] = acc.x;
    rbuf[w][1][cg] = acc.y;
    rbuf[w][2][cg] = acc.z;
    rbuf[w][3][cg] = acc.w;
    __syncthreads();

    // ---- phase B: waves 0-3 (thread j = tid < 256): reduce + gates + state ----
    if (tid < HDIM) {
      const int jjf = tid >> 6;   // wave-uniform -> conflict-free stride-1 reads
      const int cgf = tid & 63;
      float r = 0.f;
#pragma unroll
      for (int w2 = 0; w2 < 8; ++w2) r += rbuf[w2][jjf][cgf];

      const float gi = 1.f / (1.f + __expf(-(pi + r)));
      const float gf = 1.f / (1.f + __expf(-(pf + r)));
      const float gg = 1.f / (1.f + __expf(-(pg + r)));
      const float go = 1.f / (1.f + __expf(-(po + r)));
      c = gf + c + gi * gg;                                 // reference quirk: f + c + i*g
      const float th = 1.f - 2.f / (__expf(2.f * c) + 1.f); // tanh, inf-safe
      h = go + th;                                          // reference quirk: o + tanh(c)

      hidden[(size_t)t * HDIM + tid] = h;
      hbuf[tid] = h;                 // safe: all phase-A reads done at barrier above
      pi = npi; pf = npf; pg = npg; po = npo;
    }
    __syncthreads();                 // new h visible before next phase A
  }
  if (tid < HDIM) {
    out[b * HDIM + tid] = h;                 // h_t  [B,H]
    out[BATCH * HDIM + b * HDIM + tid] = c;  // c_t  [B,H]
  }
}

extern "C" void kernel_launch(void* const* d_in, const int* in_sizes, int n_in,
                              void* d_out, int out_size, void* d_ws, size_t ws_size,
                              hipStream_t stream) {
  const float* x   = (const float*)d_in[0];
  const float* hp  = (const float*)d_in[1];
  const float* wix = (const float*)d_in[2];
  const float* wih = (const float*)d_in[3];
  const float* wfx = (const float*)d_in[4];
  const float* wfh = (const float*)d_in[5];
  const float* wcx = (const float*)d_in[6];
  const float* wch = (const float*)d_in[7];
  const float* wox = (const float*)d_in[8];
  const float* woh = (const float*)d_in[9];
  const float* ui  = (const float*)d_in[10];
  const float* bi  = (const float*)d_in[11];
  float* out = (float*)d_out;

  // ws layout: Wp [512*1024] f32 (2 MB) | pre [65536*1024] f32 (256 MB)
  float* Wp  = (float*)d_ws;
  float* pre = (float*)d_ws + (size_t)KDIM * NDIM;

  hipLaunchKernelGGL(pack_w_kernel, dim3((KDIM * NDIM) / 256), dim3(256), 0, stream,
                     wix, wih, wfx, wfh, wcx, wch, wox, woh, Wp);
  hipLaunchKernelGGL(gemm_pre_kernel, dim3(NDIM / BN, (BATCH * TLEN) / BM), dim3(256), 0, stream,
                     x, hp, Wp, bi, pre);
  hipLaunchKernelGGL(scan_kernel, dim3(BATCH), dim3(512), 0, stream, pre, ui, out);
}